// Round 2
// baseline (107.664 us; speedup 1.0000x reference)
//
#include <hip/hip_runtime.h>

// SPQR dequant-GEMV: y[b][m] = sum_n x[b][n] * Wd[m][n] + CSR outlier correction
// M=N=8192, beta1=beta2=16, B(=b*l)=10, 32 nnz/row.
// R2: fix suspected VGPR spills (256-VGPR budget), RB=8, hoisted tile scalars,
//     unroll-2 chunk loop, cheap quad+LDS-tree epilogue.

constexpr int M_DIM = 8192;
constexpr int N_DIM = 8192;
constexpr int TN    = 512;          // N / 16
constexpr int BQ    = 10;           // batch (b*l)
constexpr int RB    = 8;            // rows per block (8-aligned -> one 16-row tile)
constexpr int NTHREADS = 256;
constexpr int NC    = NTHREADS * 4; // 1024 columns per chunk
constexpr int NCHUNK = N_DIM / NC;  // 8
constexpr int NOUT  = RB * BQ;      // 80 partial outputs per block

__global__ __launch_bounds__(NTHREADS, 2)
void spqr_fused(const float* __restrict__ x,
                const int*   __restrict__ W,
                const int*   __restrict__ Ws,
                const int*   __restrict__ Wz,
                const float* __restrict__ Wss,
                const float* __restrict__ Wsz,
                const float* __restrict__ Wzs,
                const float* __restrict__ Wzz,
                const int*   __restrict__ row_offsets,
                const int*   __restrict__ col_ids,
                const float* __restrict__ values,
                float*       __restrict__ y)
{
    const int t  = threadIdx.x;
    const int m0 = blockIdx.x * RB;
    const int ti = m0 >> 4;                 // all 8 rows in the same 16-row tile

    float acc[RB][BQ];
    #pragma unroll
    for (int r = 0; r < RB; ++r)
        #pragma unroll
        for (int b = 0; b < BQ; ++b)
            acc[r][b] = 0.f;

    const int tq = t * 4;

    #pragma unroll 2
    for (int chunk = 0; chunk < NCHUNK; ++chunk) {
        const int n0 = chunk * NC + tq;     // this thread's 4 columns
        const int g  = n0 >> 4;             // scale-group (same for all 4 cols)
        const int tIdx = ti * TN + g;       // block-uniform tile row -> hoisted

        // second-order tile params: one set per chunk (not per row!)
        const float wss = Wss[tIdx];
        const float wsz = Wsz[tIdx];
        const float wzs = Wzs[tIdx];
        const float wzz = Wzz[tIdx];

        // x[b][n0..n0+3] -> registers (coalesced float4, L2-resident)
        float4 xv[BQ];
        #pragma unroll
        for (int b = 0; b < BQ; ++b)
            xv[b] = *reinterpret_cast<const float4*>(x + b * N_DIM + n0);

        #pragma unroll
        for (int r = 0; r < RB; ++r) {
            const int m = m0 + r;
            const float s = ((float)Ws[m * TN + g] - wsz) * wss;
            const float z = ((float)Wz[m * TN + g] - wzz) * wzs;
            const int4 wc = *reinterpret_cast<const int4*>(W + (size_t)m * N_DIM + n0);
            const float w0 = ((float)wc.x - z) * s;
            const float w1 = ((float)wc.y - z) * s;
            const float w2 = ((float)wc.z - z) * s;
            const float w3 = ((float)wc.w - z) * s;
            #pragma unroll
            for (int b = 0; b < BQ; ++b) {
                float a = acc[r][b];
                a = fmaf(w0, xv[b].x, a);
                a = fmaf(w1, xv[b].y, a);
                a = fmaf(w2, xv[b].z, a);
                a = fmaf(w3, xv[b].w, a);
                acc[r][b] = a;
            }
        }
    }

    // ---- fused CSR outlier correction: 32 lanes per row, 8 rows = 256 threads ----
    __shared__ float lsp[RB][BQ];
    {
        const int r = t >> 5;
        const int j = t & 31;
        const int m = m0 + r;
        const int base = row_offsets[m];
        const int cnt  = row_offsets[m + 1] - base;
        float c[BQ];
        #pragma unroll
        for (int b = 0; b < BQ; ++b) c[b] = 0.f;
        for (int jj = j; jj < cnt; jj += 32) {
            const int   col = col_ids[base + jj];
            const float v   = values[base + jj];
            #pragma unroll
            for (int b = 0; b < BQ; ++b)
                c[b] = fmaf(v, x[b * N_DIM + col], c[b]);
        }
        #pragma unroll
        for (int b = 0; b < BQ; ++b) {
            float v = c[b];
            for (int off = 16; off > 0; off >>= 1)
                v += __shfl_xor(v, off, 32);
            c[b] = v;
        }
        if (j == 0) {
            #pragma unroll
            for (int b = 0; b < BQ; ++b)
                lsp[r][b] = c[b];
        }
    }

    // ---- dense reduction: 2-step quad shuffle, then LDS tree ----
    #pragma unroll
    for (int r = 0; r < RB; ++r)
        #pragma unroll
        for (int b = 0; b < BQ; ++b) {
            float v = acc[r][b];
            v += __shfl_xor(v, 1, 64);
            v += __shfl_xor(v, 2, 64);
            acc[r][b] = v;
        }

    __shared__ float lred[64][NOUT + 1];    // 64 quads x 80 outs, +1 pad
    if ((t & 3) == 0) {
        const int q = t >> 2;
        #pragma unroll
        for (int r = 0; r < RB; ++r)
            #pragma unroll
            for (int b = 0; b < BQ; ++b)
                lred[q][r * BQ + b] = acc[r][b];
    }
    __shared__ float l2[NOUT][2];
    __syncthreads();

    if (t < 2 * NOUT) {                     // 160 threads: each sums 32 quads
        const int out = t % NOUT;
        const int h   = t / NOUT;
        float v = 0.f;
        #pragma unroll
        for (int q = 0; q < 32; ++q)
            v += lred[h * 32 + q][out];
        l2[out][h] = v;
    }
    __syncthreads();

    if (t < NOUT) {                         // 80 threads: final combine + write
        const int r = t / BQ;
        const int b = t % BQ;
        y[b * M_DIM + (m0 + r)] = l2[t][0] + l2[t][1] + lsp[r][b];
    }
}

extern "C" void kernel_launch(void* const* d_in, const int* in_sizes, int n_in,
                              void* d_out, int out_size, void* d_ws, size_t ws_size,
                              hipStream_t stream)
{
    const float* x    = (const float*)d_in[0];
    const int*   W    = (const int*)  d_in[1];
    const int*   Ws   = (const int*)  d_in[2];
    const int*   Wz   = (const int*)  d_in[3];
    const float* Wss  = (const float*)d_in[4];
    const float* Wsz  = (const float*)d_in[5];
    const float* Wzs  = (const float*)d_in[6];
    const float* Wzz  = (const float*)d_in[7];
    const int*   roff = (const int*)  d_in[8];
    const int*   cids = (const int*)  d_in[9];
    const float* vals = (const float*)d_in[10];
    float* yout = (float*)d_out;

    dim3 grid(M_DIM / RB);                  // 1024 blocks
    dim3 block(NTHREADS);
    spqr_fused<<<grid, block, 0, stream>>>(x, W, Ws, Wz, Wss, Wsz, Wzs, Wzz,
                                           roff, cids, vals, yout);
}

// Round 3
// 87.524 us; speedup vs baseline: 1.2301x; 1.2301x over previous
//
#include <hip/hip_runtime.h>

// SPQR dequant-GEMV: y[b][m] = sum_n x[b][n] * Wd[m][n] + CSR outlier correction
// M=N=8192, beta1=beta2=16, B(=b*l)=10, 32 nnz/row.
// R3: register-footprint restructure (dequant-first w[4][4], b-outer FMAs),
//     nontemporal W/Ws/Wz loads (protect x in L2), per-chunk scalar hoist,
//     cheap quad+LDS-tree epilogue. RB=4, 4 waves/SIMD.

constexpr int M_DIM = 8192;
constexpr int N_DIM = 8192;
constexpr int TN    = 512;          // N / 16
constexpr int BQ    = 10;           // batch (b*l)
constexpr int RB    = 4;            // rows per block
constexpr int NTHREADS = 256;
constexpr int NC    = NTHREADS * 4; // 1024 columns per chunk
constexpr int NCHUNK = N_DIM / NC;  // 8
constexpr int NOUT  = RB * BQ;      // 40 partial outputs per block

typedef int   v4i __attribute__((ext_vector_type(4)));
typedef float v4f __attribute__((ext_vector_type(4)));

__global__ __launch_bounds__(NTHREADS, 4)
void spqr_fused(const float* __restrict__ x,
                const int*   __restrict__ W,
                const int*   __restrict__ Ws,
                const int*   __restrict__ Wz,
                const float* __restrict__ Wss,
                const float* __restrict__ Wsz,
                const float* __restrict__ Wzs,
                const float* __restrict__ Wzz,
                const int*   __restrict__ row_offsets,
                const int*   __restrict__ col_ids,
                const float* __restrict__ values,
                float*       __restrict__ y)
{
    const int t  = threadIdx.x;
    const int m0 = blockIdx.x * RB;
    const int ti = m0 >> 4;                 // all 4 rows in the same 16-row tile

    float acc[RB][BQ];
    #pragma unroll
    for (int r = 0; r < RB; ++r)
        #pragma unroll
        for (int b = 0; b < BQ; ++b)
            acc[r][b] = 0.f;

    const int tq = t * 4;

    for (int chunk = 0; chunk < NCHUNK; ++chunk) {
        const int n0 = chunk * NC + tq;     // this thread's 4 columns
        const int g  = n0 >> 4;             // scale-group (same for all 4 cols)
        const int tIdx = ti * TN + g;

        // second-order tile params: once per chunk (shared by all RB rows)
        const float wss = Wss[tIdx];
        const float wsz = Wsz[tIdx];
        const float wzs = Wzs[tIdx];
        const float wzz = Wzz[tIdx];

        // x[b][n0..n0+3] -> registers (coalesced float4, L2-resident)
        v4f xv[BQ];
        #pragma unroll
        for (int b = 0; b < BQ; ++b)
            xv[b] = *reinterpret_cast<const v4f*>(x + b * N_DIM + n0);

        // raw codes for all rows first (nontemporal: W streamed exactly once)
        v4i wc[RB];
        int sraw[RB], zraw[RB];
        #pragma unroll
        for (int r = 0; r < RB; ++r) {
            const int m = m0 + r;
            wc[r]   = __builtin_nontemporal_load(
                          reinterpret_cast<const v4i*>(W + (size_t)m * N_DIM + n0));
            sraw[r] = __builtin_nontemporal_load(Ws + m * TN + g);
            zraw[r] = __builtin_nontemporal_load(Wz + m * TN + g);
        }

        // dequantize all rows -> w[RB][4] (16 regs), then consume b-outer
        float w[RB][4];
        #pragma unroll
        for (int r = 0; r < RB; ++r) {
            const float s = ((float)sraw[r] - wsz) * wss;
            const float z = ((float)zraw[r] - wzz) * wzs;
            w[r][0] = ((float)wc[r].x - z) * s;
            w[r][1] = ((float)wc[r].y - z) * s;
            w[r][2] = ((float)wc[r].z - z) * s;
            w[r][3] = ((float)wc[r].w - z) * s;
        }

        #pragma unroll
        for (int b = 0; b < BQ; ++b) {
            const v4f xb = xv[b];
            #pragma unroll
            for (int r = 0; r < RB; ++r) {
                float a = acc[r][b];
                a = fmaf(w[r][0], xb.x, a);
                a = fmaf(w[r][1], xb.y, a);
                a = fmaf(w[r][2], xb.z, a);
                a = fmaf(w[r][3], xb.w, a);
                acc[r][b] = a;
            }
        }
    }

    // ---- fused CSR outlier correction: 32 lanes per row, 4 rows = 128 threads ----
    __shared__ float lsp[RB][BQ];
    if (t < RB * 32) {
        const int r = t >> 5;
        const int j = t & 31;
        const int m = m0 + r;
        const int base = row_offsets[m];
        const int cnt  = row_offsets[m + 1] - base;
        float c[BQ];
        #pragma unroll
        for (int b = 0; b < BQ; ++b) c[b] = 0.f;
        for (int jj = j; jj < cnt; jj += 32) {
            const int   col = col_ids[base + jj];
            const float v   = values[base + jj];
            #pragma unroll
            for (int b = 0; b < BQ; ++b)
                c[b] = fmaf(v, x[b * N_DIM + col], c[b]);
        }
        #pragma unroll
        for (int b = 0; b < BQ; ++b) {
            float v = c[b];
            for (int off = 16; off > 0; off >>= 1)
                v += __shfl_xor(v, off, 32);
            c[b] = v;
        }
        if (j == 0) {
            #pragma unroll
            for (int b = 0; b < BQ; ++b)
                lsp[r][b] = c[b];
        }
    }

    // ---- dense reduction: 2-step quad shuffle, then LDS tree ----
    #pragma unroll
    for (int r = 0; r < RB; ++r)
        #pragma unroll
        for (int b = 0; b < BQ; ++b) {
            float v = acc[r][b];
            v += __shfl_xor(v, 1, 64);
            v += __shfl_xor(v, 2, 64);
            acc[r][b] = v;
        }

    __shared__ float lred[64][NOUT + 1];    // 64 quads x 40 outs (+pad)
    if ((t & 3) == 0) {
        const int q = t >> 2;
        #pragma unroll
        for (int r = 0; r < RB; ++r)
            #pragma unroll
            for (int b = 0; b < BQ; ++b)
                lred[q][r * BQ + b] = acc[r][b];
    }
    __shared__ float l2[NOUT][2];
    __syncthreads();

    if (t < 2 * NOUT) {                     // 80 threads: each sums 32 quads
        const int out = t % NOUT;
        const int h   = t / NOUT;
        float v = 0.f;
        #pragma unroll
        for (int q = 0; q < 32; ++q)
            v += lred[h * 32 + q][out];
        l2[out][h] = v;
    }
    __syncthreads();

    if (t < NOUT) {                         // 40 threads: final combine + write
        const int r = t / BQ;
        const int b = t % BQ;
        y[b * M_DIM + (m0 + r)] = l2[t][0] + l2[t][1] + lsp[r][b];
    }
}

extern "C" void kernel_launch(void* const* d_in, const int* in_sizes, int n_in,
                              void* d_out, int out_size, void* d_ws, size_t ws_size,
                              hipStream_t stream)
{
    const float* x    = (const float*)d_in[0];
    const int*   W    = (const int*)  d_in[1];
    const int*   Ws   = (const int*)  d_in[2];
    const int*   Wz   = (const int*)  d_in[3];
    const float* Wss  = (const float*)d_in[4];
    const float* Wsz  = (const float*)d_in[5];
    const float* Wzs  = (const float*)d_in[6];
    const float* Wzz  = (const float*)d_in[7];
    const int*   roff = (const int*)  d_in[8];
    const int*   cids = (const int*)  d_in[9];
    const float* vals = (const float*)d_in[10];
    float* yout = (float*)d_out;

    dim3 grid(M_DIM / RB);                  // 2048 blocks
    dim3 block(NTHREADS);
    spqr_fused<<<grid, block, 0, stream>>>(x, W, Ws, Wz, Wss, Wsz, Wzs, Wzz,
                                           roff, cids, vals, yout);
}